// Round 9
// baseline (582.318 us; speedup 1.0000x reference)
//
#include <hip/hip_runtime.h>
#include <hip/hip_fp16.h>
#include <math.h>

#define NN      100000
#define EE      1600000
#define NPAIRS  800000
#define DIN     128
#define CC      16
#define NITERS  5
#define PPT     4                    // pairs per thread
#define NGRP    (NPAIRS / PPT)       // 200000 groups of 16 lanes
#define NEGLOGC (-2.772588722239781f)
#define FPSCALE 1048576.0f           // 2^20 fixed-point scale (agg)
#define FPINV   (1.0f / 1048576.0f)

typedef float  f4 __attribute__((ext_vector_type(4)));
typedef int    i2 __attribute__((ext_vector_type(2)));
typedef unsigned long long ull;

// ---------------------------------------------------------------------------
// helpers: fp16 <-> f32
// ---------------------------------------------------------------------------
__device__ __forceinline__ unsigned short f2h(float f) {
    return __half_as_ushort(__float2half(f));
}
__device__ __forceinline__ float h2f(unsigned short u) {
    return __half2float(__ushort_as_half(u));
}
__device__ __forceinline__ unsigned int pack_h(float lo, float hi) {
    return (unsigned int)f2h(lo) | ((unsigned int)f2h(hi) << 16);
}

// ---------------------------------------------------------------------------
// fused setup: M = sigmoid(10*param); logb0 = log_softmax(x@W+b); agg = 0
// grid = 6250 blocks of 256 (covers NN*CC == 1.6M exactly)
// ---------------------------------------------------------------------------
__global__ __launch_bounds__(256) void k_setup(
    const float* __restrict__ x, const float* __restrict__ W,
    const float* __restrict__ b, const float* __restrict__ param,
    float* __restrict__ M, float* __restrict__ logb0,
    unsigned int* __restrict__ agg32)
{
    if (blockIdx.x == 0 && threadIdx.x < CC * (CC + 1) / 2) {
        int i = threadIdx.x;
        int r = 0;
        while ((r + 1) * (r + 2) / 2 <= i) ++r;
        int c = i - r * (r + 1) / 2;
        float z = param[i] * 10.0f;
        float s = 1.0f / (1.0f + __expf(-z));
        M[r * CC + c] = s;
        if (r != c) M[c * CC + r] = s;
    }

    int idx = blockIdx.x * 256 + threadIdx.x;
    agg32[idx] = 0u;

    int node = idx >> 4;
    int cls  = idx & 15;
    const f4* xr4 = (const f4*)(x + (long)node * DIN);
    float acc = b[cls];
#pragma unroll 8
    for (int k4 = 0; k4 < DIN / 4; ++k4) {
        f4 xv = __builtin_nontemporal_load(xr4 + k4);   // x streamed once
        acc = fmaf(xv.x, W[(4 * k4 + 0) * CC + cls], acc);
        acc = fmaf(xv.y, W[(4 * k4 + 1) * CC + cls], acc);
        acc = fmaf(xv.z, W[(4 * k4 + 2) * CC + cls], acc);
        acc = fmaf(xv.w, W[(4 * k4 + 3) * CC + cls], acc);
    }
    float m = acc;
    for (int off = 8; off; off >>= 1) m = fmaxf(m, __shfl_xor(m, off, 16));
    float s = __expf(acc - m);
    for (int off = 8; off; off >>= 1) s += __shfl_xor(s, off, 16);
    logb0[idx] = acc - m - __logf(s);
}

// ---------------------------------------------------------------------------
// message update + scatter. 16 lanes per edge-pair (lane = class).
// Linear-space matvec:
//   S[c] = sum_k exp(t[k]) * M[k][c];  log_msg[c] = log S[c] - log(sum_c S[c])
// t in [-log C, ~7] -> exp fp32-safe; no max-subtraction needed.
// msg2[p*16+c] packs pair p both directions as fp16 {lo=edge 2p, hi=2p+1}.
// RD_MSG=false on iter 0 (msg == const -log C); WR_MSG=false on last iter.
//
// launch_bounds(256,4): VGPR cap 128 (was 32 at default) so the 4
// pairs/thread actually software-pipeline -- rounds 5-8 showed the kernel
// pinned at ~83-90us regardless of atomic scheme because the compiler
// serialized the dependency chain at 32 VGPRs.
//
// Scatter: round-7 scheme (best measured). Messages strictly negative,
// q = round(-n*2^20) < 2^23; per-node-class per-iter sums < 2^31 -> packed
// u64 atomicAdd of {q[2j] | q[2j+1]<<32} is exact (no cross-half carry).
// Even lanes issue edge-0's 8 u64 ops, odd lanes edge-1's.
// ---------------------------------------------------------------------------
template <bool RD_MSG, bool WR_MSG>
__global__ __launch_bounds__(256, 4) void k_edges_t(
    const i2* __restrict__ esrc2, const i2* __restrict__ edst2,
    const float* __restrict__ logb, const float* __restrict__ Mg,
    unsigned int* __restrict__ msg2, ull* __restrict__ agg8)
{
    __shared__ float sM[CC * CC];
    __shared__ float sE[PPT][16 * 40];   // per-r slice, per-group stride 40
    sM[threadIdx.x] = Mg[threadIdx.x];   // blockDim == 256
    __syncthreads();

    const int lane = threadIdx.x & 15;
    const int gl   = threadIdx.x >> 4;           // group within block (0..15)
    const int g    = blockIdx.x * 16 + gl;       // global group

    float Hrow[CC];                              // M[k][lane] (symmetric)
#pragma unroll
    for (int k = 0; k < CC; ++k) Hrow[k] = sM[k * CC + lane];

    // hoist all streamed loads (independent -> deep pipelining)
    i2 s01[PPT], d01[PPT];
    unsigned int mold[PPT];
#pragma unroll
    for (int r = 0; r < PPT; ++r) {
        int p = g + r * NGRP;
        s01[r] = __builtin_nontemporal_load(esrc2 + p);
        d01[r] = __builtin_nontemporal_load(edst2 + p);
        if (RD_MSG)
            mold[r] = __builtin_nontemporal_load(msg2 + (long)p * CC + lane);
    }

    // gather beliefs (independent random 64B-row loads, all in flight)
    float lb0[PPT], lb1[PPT];
#pragma unroll
    for (int r = 0; r < PPT; ++r) {
        lb0[r] = logb[(long)s01[r].x * CC + lane];
        lb1[r] = logb[(long)s01[r].y * CC + lane];
    }

    // exp(t) into per-r LDS slices
#pragma unroll
    for (int r = 0; r < PPT; ++r) {
        float mo0, mo1;
        if (RD_MSG) {
            mo0 = h2f((unsigned short)(mold[r] & 0xffffu));  // msg[2p]
            mo1 = h2f((unsigned short)(mold[r] >> 16));      // msg[2p+1]
        } else {
            mo0 = NEGLOGC; mo1 = NEGLOGC;
        }
        float* eb = sE[r] + gl * 40;
        eb[lane]      = __expf(lb0[r] - mo1);  // t = logb[src] - msg[reverse]
        eb[16 + lane] = __expf(lb1[r] - mo0);
    }

    // matvec (chunked: 8-reg live range) + normalize + store + scatter
#pragma unroll
    for (int r = 0; r < PPT; ++r) {
        const float* eb = sE[r] + gl * 40;
        float S0 = 0.f, S1 = 0.f;
#pragma unroll
        for (int ch = 0; ch < 4; ++ch) {
            f4 e0 = *(const f4*)(eb + 4 * ch);
            f4 e1 = *(const f4*)(eb + 16 + 4 * ch);
            S0 = fmaf(e0.x, Hrow[4 * ch + 0], S0);
            S0 = fmaf(e0.y, Hrow[4 * ch + 1], S0);
            S0 = fmaf(e0.z, Hrow[4 * ch + 2], S0);
            S0 = fmaf(e0.w, Hrow[4 * ch + 3], S0);
            S1 = fmaf(e1.x, Hrow[4 * ch + 0], S1);
            S1 = fmaf(e1.y, Hrow[4 * ch + 1], S1);
            S1 = fmaf(e1.z, Hrow[4 * ch + 2], S1);
            S1 = fmaf(e1.w, Hrow[4 * ch + 3], S1);
        }

        float T0 = S0, T1 = S1;
        for (int off = 8; off; off >>= 1) {
            T0 += __shfl_xor(T0, off, 16);
            T1 += __shfl_xor(T1, off, 16);
        }
        // one masked log covers both edges' T (T uniform within group)
        float tv = (lane & 1) ? T1 : T0;
        float lt = __logf(tv);
        float lp = __shfl_xor(lt, 1, 16);
        float lT0 = (lane & 1) ? lp : lt;
        float lT1 = (lane & 1) ? lt : lp;
        float n0 = __logf(S0) - lT0;
        float n1 = __logf(S1) - lT1;

        if (WR_MSG) {
            int p = g + r * NGRP;
            __builtin_nontemporal_store(pack_h(n0, n1),
                                        msg2 + (long)p * CC + lane);
        }

        // fixed-point packed scatter (2 classes per u64 atomic)
        unsigned int q0 = (unsigned int)(fmaxf(-n0, 0.f) * FPSCALE + 0.5f);
        unsigned int q1 = (unsigned int)(fmaxf(-n1, 0.f) * FPSCALE + 0.5f);
        unsigned int p0 = __shfl_xor(q0, 1, 16);   // partner class's q
        unsigned int p1 = __shfl_xor(q1, 1, 16);
        bool odd = lane & 1;
        ull  val  = odd ? ((ull)p1 | ((ull)q1 << 32))
                        : ((ull)q0 | ((ull)p0 << 32));
        int  node = odd ? d01[r].y : d01[r].x;
        atomicAdd(&agg8[(long)node * 8 + (lane >> 1)], val);
    }
}

// ---------------------------------------------------------------------------
// log_b = log_normalize(agg + log_b0); also resets agg for next iteration.
// agg32[n*16+c] holds the fixed-point class-c sum (little-endian u64 halves).
// ---------------------------------------------------------------------------
__global__ __launch_bounds__(256) void k_update(
    const float* __restrict__ logb0, unsigned int* __restrict__ agg32,
    float* __restrict__ out)
{
    int idx = blockIdx.x * blockDim.x + threadIdx.x;
    unsigned int q = agg32[idx];
    agg32[idx] = 0u;
    float v = fmaf(-(float)q, FPINV, logb0[idx]);
    float m = v;
    for (int off = 8; off; off >>= 1) m = fmaxf(m, __shfl_xor(m, off, 16));
    float s = __expf(v - m);
    for (int off = 8; off; off >>= 1) s += __shfl_xor(s, off, 16);
    out[idx] = v - m - __logf(s);
}

// ---------------------------------------------------------------------------
extern "C" void kernel_launch(void* const* d_in, const int* in_sizes, int n_in,
                              void* d_out, int out_size, void* d_ws, size_t ws_size,
                              hipStream_t stream)
{
    const float* x     = (const float*)d_in[0];
    const float* W     = (const float*)d_in[1];
    const float* b     = (const float*)d_in[2];
    const float* param = (const float*)d_in[3];
    const int*   eidx  = (const int*)d_in[4];
    const i2*    esrc2 = (const i2*)eidx;
    const i2*    edst2 = (const i2*)(eidx + EE);

    float* ws    = (float*)d_ws;
    float* M     = ws;                         // 256 floats
    float* logb0 = M     + 256;                // N*C
    float* logb  = logb0 + (long)NN * CC;      // N*C
    unsigned int* agg32 = (unsigned int*)(logb + (long)NN * CC);  // N*C u32 (8B-aligned)
    ull*          agg8  = (ull*)agg32;
    unsigned int* msg2  = agg32 + (long)NN * CC;                  // NPAIRS*C u32

    k_setup<<<NN * CC / 256, 256, 0, stream>>>(x, W, b, param, M, logb0, agg32);

    const float* curb = logb0;
    for (int it = 0; it < NITERS; ++it) {
        if (it == 0)
            k_edges_t<false, true><<<NGRP / 16, 256, 0, stream>>>(
                esrc2, edst2, curb, M, msg2, agg8);
        else if (it == NITERS - 1)
            k_edges_t<true, false><<<NGRP / 16, 256, 0, stream>>>(
                esrc2, edst2, curb, M, msg2, agg8);
        else
            k_edges_t<true, true><<<NGRP / 16, 256, 0, stream>>>(
                esrc2, edst2, curb, M, msg2, agg8);
        float* dst = (it == NITERS - 1) ? (float*)d_out : logb;
        k_update<<<NN * CC / 256, 256, 0, stream>>>(logb0, agg32, dst);
        curb = dst;
    }
}

// Round 10
// 574.100 us; speedup vs baseline: 1.0143x; 1.0143x over previous
//
#include <hip/hip_runtime.h>
#include <hip/hip_fp16.h>
#include <math.h>

#define NN      100000
#define EE      1600000
#define NPAIRS  800000
#define DIN     128
#define CC      16
#define NITERS  5
#define UU      4                    // mfma blocks (16 edges) per wave
#define NBLKS   (NPAIRS / 8)         // 100000 mfma blocks
#define GRID_E  (NBLKS / (UU * 4))   // 6250 blocks of 256 (4 waves)
#define NEGLOGC (-2.772588722239781f)
#define FPSCALE 1048576.0f           // 2^20 fixed-point scale (agg)
#define FPINV   (1.0f / 1048576.0f)

#if __has_builtin(__builtin_amdgcn_mfma_f32_16x16x16bf16_1k)
#define USE_1K 1
#else
#define USE_1K 0
#endif

typedef float f4  __attribute__((ext_vector_type(4)));
typedef float v4f __attribute__((ext_vector_type(4)));
typedef short v4s __attribute__((ext_vector_type(4)));
typedef short v8s __attribute__((ext_vector_type(8)));
typedef unsigned int u4v __attribute__((ext_vector_type(4)));
typedef int  i4v __attribute__((ext_vector_type(4)));
typedef unsigned long long ull;

// ---------------------------------------------------------------------------
// helpers: fp16 / bf16 <-> f32
// ---------------------------------------------------------------------------
__device__ __forceinline__ unsigned short f2h(float f) {
    return __half_as_ushort(__float2half(f));
}
__device__ __forceinline__ float h2f(unsigned short u) {
    return __half2float(__ushort_as_half(u));
}
__device__ __forceinline__ unsigned int pack_h(float lo, float hi) {
    return (unsigned int)f2h(lo) | ((unsigned int)f2h(hi) << 16);
}
__device__ __forceinline__ unsigned short f2bf(float f) {
    unsigned int u = __float_as_uint(f);
    unsigned int r = u + 0x7fffu + ((u >> 16) & 1u);   // round-nearest-even
    return (unsigned short)(r >> 16);
}

// ---------------------------------------------------------------------------
// fused setup: M = sigmoid(10*param); logb0 = log_softmax(x@W+b); agg = 0
// grid = 6250 blocks of 256 (covers NN*CC == 1.6M exactly)
// ---------------------------------------------------------------------------
__global__ __launch_bounds__(256) void k_setup(
    const float* __restrict__ x, const float* __restrict__ W,
    const float* __restrict__ b, const float* __restrict__ param,
    float* __restrict__ M, float* __restrict__ logb0,
    unsigned int* __restrict__ agg32)
{
    if (blockIdx.x == 0 && threadIdx.x < CC * (CC + 1) / 2) {
        int i = threadIdx.x;
        int r = 0;
        while ((r + 1) * (r + 2) / 2 <= i) ++r;
        int c = i - r * (r + 1) / 2;
        float z = param[i] * 10.0f;
        float s = 1.0f / (1.0f + __expf(-z));
        M[r * CC + c] = s;
        if (r != c) M[c * CC + r] = s;
    }

    int idx = blockIdx.x * 256 + threadIdx.x;
    agg32[idx] = 0u;

    int node = idx >> 4;
    int cls  = idx & 15;
    const f4* xr4 = (const f4*)(x + (long)node * DIN);
    float acc = b[cls];
#pragma unroll 8
    for (int k4 = 0; k4 < DIN / 4; ++k4) {
        f4 xv = __builtin_nontemporal_load(xr4 + k4);   // x streamed once
        acc = fmaf(xv.x, W[(4 * k4 + 0) * CC + cls], acc);
        acc = fmaf(xv.y, W[(4 * k4 + 1) * CC + cls], acc);
        acc = fmaf(xv.z, W[(4 * k4 + 2) * CC + cls], acc);
        acc = fmaf(xv.w, W[(4 * k4 + 3) * CC + cls], acc);
    }
    float m = acc;
    for (int off = 8; off; off >>= 1) m = fmaxf(m, __shfl_xor(m, off, 16));
    float s = __expf(acc - m);
    for (int off = 8; off; off >>= 1) s += __shfl_xor(s, off, 16);
    logb0[idx] = acc - m - __logf(s);
}

// ---------------------------------------------------------------------------
// MFMA edge kernel. One wave = UU blocks of 16 consecutive edges (8 pairs).
// Linear-space matvec as a 16x16x16 bf16 MFMA:
//   A[m][k] = exp(t_m[k])  (m = edge within block, k = class)
//   B[k][c] = M[k][c]      (symmetric coupling, bf16)
//   D[m][c] = S_m[c];  log_msg = log S - log(sum_c S)
// Input A layout: lane holds edge m=lane&15, classes 4q..4q+3 (q=lane>>4)
//   -> logb gather is ONE float4/lane; msg read ONE uint4/lane (pair pack).
// Output C layout: lane holds class c=lane&15 of edges 4g..4g+3 (g=lane>>4)
//   -> pairs = reg pairs (0,1),(2,3); msg store = 2 coalesced u32 stores;
//      T via 4-step width-16 butterfly; atomics = round-7 u64 packed scheme.
// No LDS, no barriers, no bank conflicts. RD_MSG=false on iter 0,
// WR_MSG=false on the last iter.
// ---------------------------------------------------------------------------
template <bool RD_MSG, bool WR_MSG>
__global__ __launch_bounds__(256) void k_edges_m(
    const int* __restrict__ esrc, const int* __restrict__ edst,
    const float* __restrict__ logb, const float* __restrict__ Mg,
    unsigned int* __restrict__ msg2, ull* __restrict__ agg8)
{
    const int lane = threadIdx.x & 63;
    const int wid  = blockIdx.x * 4 + (threadIdx.x >> 6);
    const int m    = lane & 15;      // input: edge row; output: class col
    const int q    = lane >> 4;      // input: k-quad;  output: row group

    // B fragment: B[k][n=m] from symmetric M (loaded once)
#if USE_1K
    v4s bfrag;
#pragma unroll
    for (int j = 0; j < 4; ++j)
        bfrag[j] = (short)f2bf(Mg[(4 * q + j) * CC + m]);
#else
    v8s bfrag = {0, 0, 0, 0, 0, 0, 0, 0};
    if (q < 2) {
#pragma unroll
        for (int j = 0; j < 8; ++j)
            bfrag[j] = (short)f2bf(Mg[(8 * q + j) * CC + m]);
    }
#endif

#pragma unroll
    for (int u = 0; u < UU; ++u) {
        const int  blk = wid * UU + u;
        const long eb  = (long)blk * 16;          // first edge of block
        const long pb  = (long)blk * 8;           // first pair of block
        const long p   = pb + (m >> 1);           // this lane's input pair

        int src = __builtin_nontemporal_load(esrc + eb + m);

        v4f acc = {0.f, 0.f, 0.f, 0.f};
        v4f D;
#if USE_1K
        f4 lb = *(const f4*)(logb + (long)src * CC + 4 * q);
        float mo[4];
        if (RD_MSG) {
            u4v mw = __builtin_nontemporal_load(
                (const u4v*)(msg2 + p * CC + 4 * q));
#pragma unroll
            for (int j = 0; j < 4; ++j)
                mo[j] = (m & 1) ? h2f((unsigned short)(mw[j] & 0xffffu))
                                : h2f((unsigned short)(mw[j] >> 16));
        } else {
#pragma unroll
            for (int j = 0; j < 4; ++j) mo[j] = NEGLOGC;
        }
        v4s a;
#pragma unroll
        for (int j = 0; j < 4; ++j)
            a[j] = (short)f2bf(__expf(lb[j] - mo[j]));
        D = __builtin_amdgcn_mfma_f32_16x16x16bf16_1k(a, bfrag, acc, 0, 0, 0);
#else
        v8s a = {0, 0, 0, 0, 0, 0, 0, 0};
        if (q < 2) {
            f4 lbA = *(const f4*)(logb + (long)src * CC + 8 * q);
            f4 lbB = *(const f4*)(logb + (long)src * CC + 8 * q + 4);
            float mo[8];
            if (RD_MSG) {
                u4v mwA = __builtin_nontemporal_load(
                    (const u4v*)(msg2 + p * CC + 8 * q));
                u4v mwB = __builtin_nontemporal_load(
                    (const u4v*)(msg2 + p * CC + 8 * q + 4));
#pragma unroll
                for (int j = 0; j < 4; ++j) {
                    mo[j]     = (m & 1) ? h2f((unsigned short)(mwA[j] & 0xffffu))
                                        : h2f((unsigned short)(mwA[j] >> 16));
                    mo[4 + j] = (m & 1) ? h2f((unsigned short)(mwB[j] & 0xffffu))
                                        : h2f((unsigned short)(mwB[j] >> 16));
                }
            } else {
#pragma unroll
                for (int j = 0; j < 8; ++j) mo[j] = NEGLOGC;
            }
#pragma unroll
            for (int j = 0; j < 4; ++j) {
                a[j]     = (short)f2bf(__expf(lbA[j] - mo[j]));
                a[4 + j] = (short)f2bf(__expf(lbB[j] - mo[4 + j]));
            }
        }
        D = __builtin_amdgcn_mfma_f32_16x16x32_bf16(a, bfrag, acc, 0, 0, 0);
#endif

        // T[i] = per-edge class sum (butterfly within the 16-lane group)
        v4f T = D;
#pragma unroll
        for (int off = 1; off < 16; off <<= 1) {
#pragma unroll
            for (int i = 0; i < 4; ++i) T[i] += __shfl_xor(T[i], off, 16);
        }
        float n0 = __logf(D[0]) - __logf(T[0]);
        float n1 = __logf(D[1]) - __logf(T[1]);
        float n2 = __logf(D[2]) - __logf(T[2]);
        float n3 = __logf(D[3]) - __logf(T[3]);

        if (WR_MSG) {
            // rows (4q,4q+1) = pair pb+2q; rows (4q+2,4q+3) = pair pb+2q+1
            __builtin_nontemporal_store(pack_h(n0, n1),
                                        msg2 + (pb + 2 * q) * CC + m);
            __builtin_nontemporal_store(pack_h(n2, n3),
                                        msg2 + (pb + 2 * q + 1) * CC + m);
        }

        // packed u64 fixed-point scatter (2 classes per atomic)
        i4v d4 = *(const i4v*)(edst + eb + 4 * q);
        float nv[4] = {n0, n1, n2, n3};
#pragma unroll
        for (int i = 0; i < 4; ++i) {
            unsigned int qv = (unsigned int)(fmaxf(-nv[i], 0.f) * FPSCALE + 0.5f);
            unsigned int pv = __shfl_xor(qv, 1, 16);   // class m^1, same edge
            if (!(m & 1)) {
                ull val = (ull)qv | ((ull)pv << 32);
                atomicAdd(&agg8[(long)d4[i] * 8 + (m >> 1)], val);
            }
        }
    }
}

// ---------------------------------------------------------------------------
// log_b = log_normalize(agg + log_b0); also resets agg for next iteration.
// agg32[n*16+c] holds the fixed-point class-c sum (little-endian u64 halves).
// ---------------------------------------------------------------------------
__global__ __launch_bounds__(256) void k_update(
    const float* __restrict__ logb0, unsigned int* __restrict__ agg32,
    float* __restrict__ out)
{
    int idx = blockIdx.x * blockDim.x + threadIdx.x;
    unsigned int q = agg32[idx];
    agg32[idx] = 0u;
    float v = fmaf(-(float)q, FPINV, logb0[idx]);
    float m = v;
    for (int off = 8; off; off >>= 1) m = fmaxf(m, __shfl_xor(m, off, 16));
    float s = __expf(v - m);
    for (int off = 8; off; off >>= 1) s += __shfl_xor(s, off, 16);
    out[idx] = v - m - __logf(s);
}

// ---------------------------------------------------------------------------
extern "C" void kernel_launch(void* const* d_in, const int* in_sizes, int n_in,
                              void* d_out, int out_size, void* d_ws, size_t ws_size,
                              hipStream_t stream)
{
    const float* x     = (const float*)d_in[0];
    const float* W     = (const float*)d_in[1];
    const float* b     = (const float*)d_in[2];
    const float* param = (const float*)d_in[3];
    const int*   eidx  = (const int*)d_in[4];
    const int*   esrc  = eidx;
    const int*   edst  = eidx + EE;

    float* ws    = (float*)d_ws;
    float* M     = ws;                         // 256 floats
    float* logb0 = M     + 256;                // N*C
    float* logb  = logb0 + (long)NN * CC;      // N*C
    unsigned int* agg32 = (unsigned int*)(logb + (long)NN * CC);  // N*C u32 (8B-aligned)
    ull*          agg8  = (ull*)agg32;
    unsigned int* msg2  = agg32 + (long)NN * CC;                  // NPAIRS*C u32

    k_setup<<<NN * CC / 256, 256, 0, stream>>>(x, W, b, param, M, logb0, agg32);

    const float* curb = logb0;
    for (int it = 0; it < NITERS; ++it) {
        if (it == 0)
            k_edges_m<false, true><<<GRID_E, 256, 0, stream>>>(
                esrc, edst, curb, M, msg2, agg8);
        else if (it == NITERS - 1)
            k_edges_m<true, false><<<GRID_E, 256, 0, stream>>>(
                esrc, edst, curb, M, msg2, agg8);
        else
            k_edges_m<true, true><<<GRID_E, 256, 0, stream>>>(
                esrc, edst, curb, M, msg2, agg8);
        float* dst = (it == NITERS - 1) ? (float*)d_out : logb;
        k_update<<<NN * CC / 256, 256, 0, stream>>>(logb0, agg32, dst);
        curb = dst;
    }
}

// Round 11
// 573.276 us; speedup vs baseline: 1.0158x; 1.0014x over previous
//
#include <hip/hip_runtime.h>
#include <hip/hip_fp16.h>
#include <math.h>

#define NN      100000
#define EE      1600000
#define NPAIRS  800000
#define DIN     128
#define CC      16
#define NITERS  5
#define UU      4                    // mfma blocks (16 edges) per wave
#define NBLKS   (NPAIRS / 8)         // 100000 mfma blocks
#define GRID_E  (NBLKS / (UU * 4))   // 6250 blocks of 256 (4 waves)
#define NEGLOGC (-2.772588722239781f)
#define FPSCALE 1048576.0f           // 2^20 fixed-point scale (agg)
#define FPINV   (1.0f / 1048576.0f)

#if __has_builtin(__builtin_amdgcn_mfma_f32_16x16x16bf16_1k)
#define USE_1K 1
#else
#define USE_1K 0
#endif

typedef float f4  __attribute__((ext_vector_type(4)));
typedef float v4f __attribute__((ext_vector_type(4)));
typedef short v4s __attribute__((ext_vector_type(4)));
typedef short v8s __attribute__((ext_vector_type(8)));
typedef unsigned int u4v __attribute__((ext_vector_type(4)));
typedef int  i4v __attribute__((ext_vector_type(4)));
typedef unsigned long long ull;

// ---------------------------------------------------------------------------
// helpers: fp16 / bf16 <-> f32
// ---------------------------------------------------------------------------
__device__ __forceinline__ unsigned short f2h(float f) {
    return __half_as_ushort(__float2half(f));
}
__device__ __forceinline__ float h2f(unsigned short u) {
    return __half2float(__ushort_as_half(u));
}
__device__ __forceinline__ unsigned int pack_h(float lo, float hi) {
    return (unsigned int)f2h(lo) | ((unsigned int)f2h(hi) << 16);
}
__device__ __forceinline__ unsigned short f2bf(float f) {
    unsigned int u = __float_as_uint(f);
    unsigned int r = u + 0x7fffu + ((u >> 16) & 1u);   // round-nearest-even
    return (unsigned short)(r >> 16);
}

// ---------------------------------------------------------------------------
// fused setup: M = sigmoid(10*param) (+ row sums at M[256..271]);
// logb0 = log_softmax(x@W+b); agg = 0
// grid = 6250 blocks of 256 (covers NN*CC == 1.6M exactly)
// ---------------------------------------------------------------------------
__global__ __launch_bounds__(256) void k_setup(
    const float* __restrict__ x, const float* __restrict__ W,
    const float* __restrict__ b, const float* __restrict__ param,
    float* __restrict__ M, float* __restrict__ logb0,
    unsigned int* __restrict__ agg32)
{
    if (blockIdx.x == 0) {
        if (threadIdx.x < CC * (CC + 1) / 2) {
            int i = threadIdx.x;
            int r = 0;
            while ((r + 1) * (r + 2) / 2 <= i) ++r;
            int c = i - r * (r + 1) / 2;
            float z = param[i] * 10.0f;
            float s = 1.0f / (1.0f + __expf(-z));
            M[r * CC + c] = s;
            if (r != c) M[c * CC + r] = s;
        }
        __syncthreads();                       // block-0-local barrier
        if (threadIdx.x < CC) {                // row sums for the T shortcut
            float s = 0.f;
            for (int c = 0; c < CC; ++c) s += M[threadIdx.x * CC + c];
            M[256 + threadIdx.x] = s;
        }
    }

    int idx = blockIdx.x * 256 + threadIdx.x;
    agg32[idx] = 0u;

    int node = idx >> 4;
    int cls  = idx & 15;
    const f4* xr4 = (const f4*)(x + (long)node * DIN);
    float acc = b[cls];
#pragma unroll 8
    for (int k4 = 0; k4 < DIN / 4; ++k4) {
        f4 xv = __builtin_nontemporal_load(xr4 + k4);   // x streamed once
        acc = fmaf(xv.x, W[(4 * k4 + 0) * CC + cls], acc);
        acc = fmaf(xv.y, W[(4 * k4 + 1) * CC + cls], acc);
        acc = fmaf(xv.z, W[(4 * k4 + 2) * CC + cls], acc);
        acc = fmaf(xv.w, W[(4 * k4 + 3) * CC + cls], acc);
    }
    float m = acc;
    for (int off = 8; off; off >>= 1) m = fmaxf(m, __shfl_xor(m, off, 16));
    float s = __expf(acc - m);
    for (int off = 8; off; off >>= 1) s += __shfl_xor(s, off, 16);
    logb0[idx] = acc - m - __logf(s);
}

// ---------------------------------------------------------------------------
// MFMA edge kernel with HOISTED multi-chain loads.
// One wave = UU blocks of 16 consecutive edges (8 pairs).
//   A[m][k] = exp(t_m[k]), B[k][c] = M[k][c], D = A*B (16x16x16 bf16 MFMA).
// Round-10 post-mortem: VGPR=24 showed the compiler serialized the UU
// chains (load->gather->exp->mfma->log->atomic ~2000cyc each, 4 in series
// = the measured ~7900 cyc/wave). Here all UU blocks' src/edst/msg/logb
// loads are issued into DISTINCT registers before any compute.
// T shortcut: T_m = sum_k e_mk * rowsum(M)_k computed in fp32 A-layout
// (4 FMA + 2 width-64 shuffles), log(T) once per edge then shuffled into
// C-layout (1 log instead of 4; butterfly eliminated).
// RD_MSG=false on iter 0, WR_MSG=false on the last iter.
// ---------------------------------------------------------------------------
template <bool RD_MSG, bool WR_MSG>
__global__ __launch_bounds__(256) void k_edges_m(
    const int* __restrict__ esrc, const int* __restrict__ edst,
    const float* __restrict__ logb, const float* __restrict__ Mg,
    unsigned int* __restrict__ msg2, ull* __restrict__ agg8)
{
    const int lane = threadIdx.x & 63;
    const int wid  = blockIdx.x * 4 + (threadIdx.x >> 6);
    const int m    = lane & 15;      // input: edge row; output: class col
    const int q    = lane >> 4;      // input: k-quad;  output: row group

#if USE_1K
    // B fragment: B[k][n=m] from symmetric M (loaded once)
    v4s bfrag;
#pragma unroll
    for (int j = 0; j < 4; ++j)
        bfrag[j] = (short)f2bf(Mg[(4 * q + j) * CC + m]);
    f4 rs = *(const f4*)(Mg + 256 + 4 * q);    // rowsums for k = 4q..4q+3

    // ---- phase 1: hoist ALL UU blocks' loads into distinct registers ----
    int src[UU];
    i4v d4[UU];
    u4v mw[UU];
    f4  lb[UU];
#pragma unroll
    for (int u = 0; u < UU; ++u) {
        const long eb = (long)(wid * UU + u) * 16;
        src[u] = __builtin_nontemporal_load(esrc + eb + m);
        d4[u]  = *(const i4v*)(edst + eb + 4 * q);
    }
#pragma unroll
    for (int u = 0; u < UU; ++u) {
        const long p = (long)(wid * UU + u) * 8 + (m >> 1);
        if (RD_MSG)
            mw[u] = __builtin_nontemporal_load((const u4v*)(msg2 + p * CC + 4 * q));
        lb[u] = *(const f4*)(logb + (long)src[u] * CC + 4 * q);
    }

    // ---- phase 2: compute (4 independent chains already in flight) ----
#pragma unroll
    for (int u = 0; u < UU; ++u) {
        const long pb = (long)(wid * UU + u) * 8;

        float e[4], Tm = 0.f;
#pragma unroll
        for (int j = 0; j < 4; ++j) {
            float mo = NEGLOGC;
            if (RD_MSG)
                mo = (m & 1) ? h2f((unsigned short)(mw[u][j] & 0xffffu))
                             : h2f((unsigned short)(mw[u][j] >> 16));
            e[j] = __expf(lb[u][j] - mo);   // t = logb[src] - msg[reverse]
            Tm   = fmaf(e[j], rs[j], Tm);
        }
        // combine k-quads: lanes {m,m+16,m+32,m+48} hold partials of edge m
        Tm += __shfl_xor(Tm, 16, 64);
        Tm += __shfl_xor(Tm, 32, 64);
        float ltA = __logf(Tm);              // log T[edge = lane&15]

        v4s a;
#pragma unroll
        for (int j = 0; j < 4; ++j) a[j] = (short)f2bf(e[j]);
        v4f acc = {0.f, 0.f, 0.f, 0.f};
        v4f D = __builtin_amdgcn_mfma_f32_16x16x16bf16_1k(a, bfrag, acc, 0, 0, 0);

        float n[4];
#pragma unroll
        for (int i = 0; i < 4; ++i) {
            float lT = __shfl(ltA, 4 * q + i, 16);   // log T[edge 4q+i]
            n[i] = __logf(D[i]) - lT;
        }

        if (WR_MSG) {
            // rows (4q,4q+1) = pair pb+2q; rows (4q+2,4q+3) = pair pb+2q+1
            __builtin_nontemporal_store(pack_h(n[0], n[1]),
                                        msg2 + (pb + 2 * q) * CC + m);
            __builtin_nontemporal_store(pack_h(n[2], n[3]),
                                        msg2 + (pb + 2 * q + 1) * CC + m);
        }

        // packed u64 fixed-point scatter (2 classes per atomic)
#pragma unroll
        for (int i = 0; i < 4; ++i) {
            unsigned int qv = (unsigned int)(fmaxf(-n[i], 0.f) * FPSCALE + 0.5f);
            unsigned int pv = __shfl_xor(qv, 1, 16);   // class m^1, same edge
            if (!(m & 1)) {
                ull val = (ull)qv | ((ull)pv << 32);
                atomicAdd(&agg8[(long)d4[u][i] * 8 + (m >> 1)], val);
            }
        }
    }
#else
    // fallback: 16x16x32 bf16 with zero-padded K (round-10 verified body)
    v8s bfrag = {0, 0, 0, 0, 0, 0, 0, 0};
    if (q < 2) {
#pragma unroll
        for (int j = 0; j < 8; ++j)
            bfrag[j] = (short)f2bf(Mg[(8 * q + j) * CC + m]);
    }
#pragma unroll
    for (int u = 0; u < UU; ++u) {
        const int  blk = wid * UU + u;
        const long eb  = (long)blk * 16;
        const long pb  = (long)blk * 8;
        const long p   = pb + (m >> 1);
        int src = __builtin_nontemporal_load(esrc + eb + m);
        v8s a = {0, 0, 0, 0, 0, 0, 0, 0};
        if (q < 2) {
            f4 lbA = *(const f4*)(logb + (long)src * CC + 8 * q);
            f4 lbB = *(const f4*)(logb + (long)src * CC + 8 * q + 4);
            float mo[8];
            if (RD_MSG) {
                u4v mwA = __builtin_nontemporal_load((const u4v*)(msg2 + p * CC + 8 * q));
                u4v mwB = __builtin_nontemporal_load((const u4v*)(msg2 + p * CC + 8 * q + 4));
#pragma unroll
                for (int j = 0; j < 4; ++j) {
                    mo[j]     = (m & 1) ? h2f((unsigned short)(mwA[j] & 0xffffu))
                                        : h2f((unsigned short)(mwA[j] >> 16));
                    mo[4 + j] = (m & 1) ? h2f((unsigned short)(mwB[j] & 0xffffu))
                                        : h2f((unsigned short)(mwB[j] >> 16));
                }
            } else {
#pragma unroll
                for (int j = 0; j < 8; ++j) mo[j] = NEGLOGC;
            }
#pragma unroll
            for (int j = 0; j < 4; ++j) {
                a[j]     = (short)f2bf(__expf(lbA[j] - mo[j]));
                a[4 + j] = (short)f2bf(__expf(lbB[j] - mo[4 + j]));
            }
        }
        v4f acc = {0.f, 0.f, 0.f, 0.f};
        v4f D = __builtin_amdgcn_mfma_f32_16x16x32_bf16(a, bfrag, acc, 0, 0, 0);
        v4f T = D;
#pragma unroll
        for (int off = 1; off < 16; off <<= 1) {
#pragma unroll
            for (int i = 0; i < 4; ++i) T[i] += __shfl_xor(T[i], off, 16);
        }
        float n[4];
#pragma unroll
        for (int i = 0; i < 4; ++i) n[i] = __logf(D[i]) - __logf(T[i]);
        if (WR_MSG) {
            __builtin_nontemporal_store(pack_h(n[0], n[1]), msg2 + (pb + 2 * q) * CC + m);
            __builtin_nontemporal_store(pack_h(n[2], n[3]), msg2 + (pb + 2 * q + 1) * CC + m);
        }
        i4v d4 = *(const i4v*)(edst + eb + 4 * q);
#pragma unroll
        for (int i = 0; i < 4; ++i) {
            unsigned int qv = (unsigned int)(fmaxf(-n[i], 0.f) * FPSCALE + 0.5f);
            unsigned int pv = __shfl_xor(qv, 1, 16);
            if (!(m & 1)) {
                ull val = (ull)qv | ((ull)pv << 32);
                atomicAdd(&agg8[(long)d4[i] * 8 + (m >> 1)], val);
            }
        }
    }
#endif
}

// ---------------------------------------------------------------------------
// log_b = log_normalize(agg + log_b0); also resets agg for next iteration.
// agg32[n*16+c] holds the fixed-point class-c sum (little-endian u64 halves).
// ---------------------------------------------------------------------------
__global__ __launch_bounds__(256) void k_update(
    const float* __restrict__ logb0, unsigned int* __restrict__ agg32,
    float* __restrict__ out)
{
    int idx = blockIdx.x * blockDim.x + threadIdx.x;
    unsigned int q = agg32[idx];
    agg32[idx] = 0u;
    float v = fmaf(-(float)q, FPINV, logb0[idx]);
    float m = v;
    for (int off = 8; off; off >>= 1) m = fmaxf(m, __shfl_xor(m, off, 16));
    float s = __expf(v - m);
    for (int off = 8; off; off >>= 1) s += __shfl_xor(s, off, 16);
    out[idx] = v - m - __logf(s);
}

// ---------------------------------------------------------------------------
extern "C" void kernel_launch(void* const* d_in, const int* in_sizes, int n_in,
                              void* d_out, int out_size, void* d_ws, size_t ws_size,
                              hipStream_t stream)
{
    const float* x     = (const float*)d_in[0];
    const float* W     = (const float*)d_in[1];
    const float* b     = (const float*)d_in[2];
    const float* param = (const float*)d_in[3];
    const int*   eidx  = (const int*)d_in[4];
    const int*   esrc  = eidx;
    const int*   edst  = eidx + EE;

    float* ws    = (float*)d_ws;
    float* M     = ws;                         // 256 + 16 rowsums (pad 288)
    float* logb0 = M     + 288;                // N*C
    float* logb  = logb0 + (long)NN * CC;      // N*C
    unsigned int* agg32 = (unsigned int*)(logb + (long)NN * CC);  // N*C u32 (8B-aligned)
    ull*          agg8  = (ull*)agg32;
    unsigned int* msg2  = agg32 + (long)NN * CC;                  // NPAIRS*C u32

    k_setup<<<NN * CC / 256, 256, 0, stream>>>(x, W, b, param, M, logb0, agg32);

    const float* curb = logb0;
    for (int it = 0; it < NITERS; ++it) {
        if (it == 0)
            k_edges_m<false, true><<<GRID_E, 256, 0, stream>>>(
                esrc, edst, curb, M, msg2, agg8);
        else if (it == NITERS - 1)
            k_edges_m<true, false><<<GRID_E, 256, 0, stream>>>(
                esrc, edst, curb, M, msg2, agg8);
        else
            k_edges_m<true, true><<<GRID_E, 256, 0, stream>>>(
                esrc, edst, curb, M, msg2, agg8);
        float* dst = (it == NITERS - 1) ? (float*)d_out : logb;
        k_update<<<NN * CC / 256, 256, 0, stream>>>(logb0, agg32, dst);
        curb = dst;
    }
}